// Round 7
// baseline (134.966 us; speedup 1.0000x reference)
//
#include <hip/hip_runtime.h>
#include <math.h>

// Problem constants (fixed by the reference).
#define NITEMS 50000
#define BATCH  512
#define LLEN   50
#define KTOP   20
#define HDIM   32
#define DDIM   32
#define NCH    5
#define NSEG   33             // H+1 piecewise-linear segments
#define NSCAL  200            // scalars per item
#define NCELL  100            // (c,k) cells
#define THRP   33             // padded LDS stride for sorted thresholds
#define NWAVE  8              // waves per block
#define CSLOT  13             // ceil(100/8) cells per 8-lane group

typedef _Float16 h2 __attribute__((ext_vector_type(2)));

static __device__ __forceinline__ float dot2_acc(h2 a, h2 b, float c) {
#if __has_builtin(__builtin_amdgcn_fdot2)
    return __builtin_amdgcn_fdot2(a, b, c, false);
#else
    return fmaf((float)a.x, (float)b.x, fmaf((float)a.y, (float)b.y, c));
#endif
}

// ws layout (floats):
//   [0, 160)       sorted thr[c][0..31] (ascending per channel)
//   [160, 5440)    AB16 table: 5280 uints, fp16 swizzled (see below)
//   [5440, 5952)   row order (ints) from the length sort
#define WS_THRS  0
#define WS_AB16  160
#define WS_ORDER 5440

// fp16 table layout: row (c,s) = 32 uints (128 B).  Chunk d4 (0..7) = 4
// uints: [A(4d4,4d4+1), B(4d4,4d4+1), A(4d4+2,4d4+3), B(4d4+2,4d4+3)]
// where A(a,b) packs halves (lo=A_a, hi=A_b).  A lane's b128 read of its
// chunk is directly v_pk_fma_f16-ready (R7: halves both LDS bytes and
// instruction count vs the fp32 (A,B)-pair layout).

// ---------------------------------------------------------------------------
// Setup + sort, one dispatch. Blocks 0..32: per-(channel, segment) affine
// coeffs of the scalar MLP (piecewise-linear decomposition; segment
// s = #{h : thr_h < x}), written as the swizzled fp16 table.  Block 0 also
// writes per-channel SORTED thresholds (sRank is the sort permutation).
// Block 33: bitonic sort of the 512 lens -> perf-only row permutation.
// ---------------------------------------------------------------------------
__global__ __launch_bounds__(256) void cnn_setup(
        const float* __restrict__ W1, const float* __restrict__ b1,
        const float* __restrict__ W2, const float* __restrict__ b2,
        const int* __restrict__ user_lens,
        float* __restrict__ ws, int* __restrict__ order) {
    const int tid = threadIdx.x;

    if (blockIdx.x < NSEG) {
        __shared__ float sW1[NCH*HDIM], sB1[NCH*HDIM], sThr[NCH*HDIM];
        __shared__ int   sRank[NCH*HDIM];
        __shared__ float sW2[NCH*HDIM*DDIM];     // 20 KB
        __shared__ float sB2[NCH*DDIM];

        for (int i = tid; i < NCH*HDIM; i += 256) { sW1[i] = W1[i]; sB1[i] = b1[i]; }
        for (int i = tid; i < NCH*HDIM*DDIM; i += 256) sW2[i] = W2[i];
        for (int i = tid; i < NCH*DDIM; i += 256) sB2[i] = b2[i];
        __syncthreads();

        for (int i = tid; i < NCH*HDIM; i += 256) {
            float w = sW1[i];
            sThr[i] = (w != 0.f) ? (-sB1[i] / w) : INFINITY;
        }
        __syncthreads();

        for (int i = tid; i < NCH*HDIM; i += 256) {
            int c = i / HDIM, h = i % HDIM;
            float thr = sThr[i];
            int rank = 0;
            for (int h2i = 0; h2i < HDIM; ++h2i) {
                float thr2 = sThr[c*HDIM + h2i];
                rank += (thr2 < thr || (thr2 == thr && h2i < h)) ? 1 : 0;
            }
            sRank[i] = rank;
            // sorted thresholds: sorted[rank] = thr  (rank is a permutation)
            if (blockIdx.x == 0) ws[WS_THRS + c*HDIM + rank] = thr;
        }
        __syncthreads();

        const int s = blockIdx.x;                 // segment
        if (tid < NCH*DDIM) {
            int c = tid / DDIM, d = tid % DDIM;
            float A = 0.f, Bv = 0.f;
#pragma unroll
            for (int h = 0; h < HDIM; ++h) {
                float w  = sW1[c*HDIM + h];
                float bb = sB1[c*HDIM + h];
                int   r  = sRank[c*HDIM + h];
                bool active = (w > 0.f) ? (r < s) : ((w < 0.f) ? (r >= s) : (bb > 0.f));
                if (active) {
                    float w2 = sW2[(c*HDIM + h)*DDIM + d];
                    A  = fmaf(w,  w2, A);
                    Bv = fmaf(bb, w2, Bv);
                }
            }
            Bv += sB2[c*DDIM + d];
            // swizzled fp16 store (see layout comment above)
            unsigned short* ab = (unsigned short*)(ws + WS_AB16);
            int d4 = d >> 2, dd = d & 3;
            int base = ((c*NSEG + s)*32 + d4*4)*2;          // ushort index
            _Float16 ah = (_Float16)A, bh = (_Float16)Bv;
            ab[base + 4*(dd>>1) + (dd&1)]     = __builtin_bit_cast(unsigned short, ah);
            ab[base + 4*(dd>>1) + 2 + (dd&1)] = __builtin_bit_cast(unsigned short, bh);
        }
    } else {
        // ---- bitonic sort of (len, row), 256 threads over 512 elements ----
        __shared__ int k512[BATCH], v512[BATCH];
        for (int i = tid; i < BATCH; i += 256) { k512[i] = user_lens[i]; v512[i] = i; }
        __syncthreads();
        for (int k = 2; k <= BATCH; k <<= 1) {
            for (int j = k >> 1; j > 0; j >>= 1) {
                int i   = ((tid & ~(j - 1)) << 1) | (tid & (j - 1));
                int ixj = i | j;
                bool up = ((i & k) == 0);
                int ka = k512[i], kb = k512[ixj];
                if ((ka > kb) == up) {
                    k512[i] = kb; k512[ixj] = ka;
                    int va = v512[i]; v512[i] = v512[ixj]; v512[ixj] = va;
                }
                __syncthreads();
            }
        }
        for (int i = tid; i < BATCH; i += 256) order[i] = v512[i];
    }
}

// ---------------------------------------------------------------------------
// Main (R7): wave-autonomous items (8 waves/block, one row/block, stripe
// w, w+8, ...), fp16 AB table, 8-lane cell groups with 4 d's per lane.
// Phase C per item-unit: 13 slots x 3 ds_read_b128 (vs R6's 25 x 3) --
// R6 post-mortem showed main ~85% LDS-issue-bound at ~1100 cyc/unit; this
// cuts it to ~670.  Accumulation: v_pk_fma_f16 affine + v_dot2_f32_f16
// into fp32 acc (error ~1e-3 pre-sigmoid, threshold 1e-2).
// ---------------------------------------------------------------------------
__global__ __launch_bounds__(512, 4) void cnn_main(
        const float* __restrict__ ctx,  const float* __restrict__ ws,
        const float* __restrict__ Wout, const float* __restrict__ bout,
        const int* __restrict__ item_idxs, const int* __restrict__ user_items,
        const int* __restrict__ user_lens, const int* __restrict__ order,
        float* __restrict__ out) {
    __shared__ unsigned int sAB16[NCH*NSEG*32];  // 21120 B, swizzled fp16
    __shared__ float  sThrS[NCH*THRP];           // sorted thr, stride 33
    __shared__ float4 sxo[NWAVE][NCELL];         // per-wave {x0,x1,off0|off1<<16,pad}
    __shared__ union WScr {                      // per-wave scratch (race-free:
        float rawx[NSCAL];                       //  own-wave use only)
        float pRed[NCELL];
    } wscr[NWAVE];

    const int tid  = threadIdx.x;
    const int w    = tid >> 6;              // wave 0..7
    const int lane = tid & 63;
    const int g    = lane >> 3;             // cell sub-group 0..7
    const int d4   = lane & 7;              // covers d = 4*d4 .. 4*d4+3

    // Stage fp16 table + sorted thresholds.
    const uint4* ABg = reinterpret_cast<const uint4*>(ws + WS_AB16);
    uint4* sAB4 = reinterpret_cast<uint4*>(sAB16);
    for (int i = tid; i < NCH*NSEG*8; i += 512) sAB4[i] = ABg[i];
    for (int i = tid; i < NCH*THRP; i += 512) {
        int c = i / THRP, j = i - c*THRP;
        sThrS[i] = (j < HDIM) ? ws[WS_THRS + c*HDIM + j] : 0.f;
    }

    // Sorted pairing (ranks r and 511-r co-resident under round-robin).
    const int rank = (blockIdx.x < 256) ? blockIdx.x : (767 - blockIdx.x);
    const int b    = order[rank];
    const int len  = user_lens[b];          // >= 1
    const float inv_len = 1.f / (float)len;
    const float bo = bout[0];
    const float w0 = Wout[4*d4], w1 = Wout[4*d4+1],
                w2 = Wout[4*d4+2], w3 = Wout[4*d4+3];

    // Per-(lane,round) phase-S constants (fixed across items).
    int sc[4], sdx[4], sdo[4];
#pragma unroll
    for (int r = 0; r < 4; ++r) {
        int idx  = lane + 64*r;
        int c    = idx / 40, rr = idx - c*40;
        int cell = c*KTOP + (rr % KTOP);
        int p    = rr / KTOP;
        sc[r]  = c;
        sdx[r] = cell*16 + p*4;             // byte offset of x0/x1 in sxo[w]
        sdo[r] = cell*16 + 8 + p*2;         // byte offset of off half-word
    }

    const int nstripe = (len > w) ? ((len - w + NWAVE - 1) / NWAVE) : 0;
    const int nj = 1 + nstripe;             // j=0 is the target item

    h2    wtA[CSLOT], wtB[CSLOT];           // target rep * Wout, packed fp16
    float acc[CSLOT];
#pragma unroll
    for (int i = 0; i < CSLOT; ++i) acc[i] = 0.f;

    __syncthreads();                        // staging visible to all waves

    // Preload target row (j = 0).
    float4 x4 = make_float4(0.f, 0.f, 0.f, 0.f);
    {
        int it0 = item_idxs[b];
        if (lane < 50) x4 = *((const float4*)(ctx + (size_t)it0*NSCAL) + lane);
    }

    char* sxoB = (char*)&sxo[w][0];
    for (int j = 0; j < nj; ++j) {
        // stage this item's scalars into the per-wave scratch
        if (lane < 50) *((float4*)&wscr[w].rawx[0] + lane) = x4;
        __builtin_amdgcn_wave_barrier();

        // prefetch next item's row (latency hidden behind S+C, no barrier)
        float4 xn4 = make_float4(0.f, 0.f, 0.f, 0.f);
        if (j + 1 < nj) {
            int nit = user_items[b*LLEN + w + NWAVE*j];
            if (lane < 50) xn4 = *((const float4*)(ctx + (size_t)nit*NSCAL) + lane);
        }

        // ---- phase S: binary-search segment for this wave's 200 scalars --
#pragma unroll
        for (int r = 0; r < 4; ++r) {
            int idx = lane + 64*r;
            if (idx < NSCAL) {
                float xv = wscr[w].rawx[idx];
                int base = sc[r]*THRP;
                int pos = 0;
                pos += (sThrS[base + pos + 15] < xv) ? 16 : 0;
                pos += (sThrS[base + pos + 7]  < xv) ? 8  : 0;
                pos += (sThrS[base + pos + 3]  < xv) ? 4  : 0;
                pos += (sThrS[base + pos + 1]  < xv) ? 2  : 0;
                pos += (sThrS[base + pos]      < xv) ? 1  : 0;
                int off = (sc[r]*NSEG + pos) << 7;   // byte offset of 128 B row
                *(float*)(sxoB + sdx[r]) = xv;
                *(unsigned short*)(sxoB + sdo[r]) = (unsigned short)off;
            }
        }
        __builtin_amdgcn_wave_barrier();

        // ---- phase C: 100 cells x 32 d by this wave alone ----------------
#pragma unroll
        for (int i = 0; i < CSLOT; ++i) {
            int cell = g + 8*i;
            if (cell < NCELL) {
                float4 xo = sxo[w][cell];
                unsigned int offs = __builtin_bit_cast(unsigned int, xo.z);
                const uint4* p0 = (const uint4*)((const char*)sAB16 + (offs & 0xffffu) + (d4 << 4));
                const uint4* p1 = (const uint4*)((const char*)sAB16 + (offs >> 16)     + (d4 << 4));
                uint4 q0 = *p0, q1 = *p1;
                _Float16 x0h = (_Float16)xo.x, x1h = (_Float16)xo.y;
                h2 x0 = {x0h, x0h}, x1 = {x1h, x1h};
                h2 o0a = x0 * __builtin_bit_cast(h2, q0.x) + __builtin_bit_cast(h2, q0.y);
                h2 o0b = x0 * __builtin_bit_cast(h2, q0.z) + __builtin_bit_cast(h2, q0.w);
                h2 o1a = x1 * __builtin_bit_cast(h2, q1.x) + __builtin_bit_cast(h2, q1.y);
                h2 o1b = x1 * __builtin_bit_cast(h2, q1.z) + __builtin_bit_cast(h2, q1.w);
                h2 repa = o0a * o1a;                  // rep for d = 4d4, 4d4+1
                h2 repb = o0b * o1b;                  // rep for d = 4d4+2, 4d4+3
                if (j == 0) {
                    // target item: fold rep_t * Wout into packed registers
                    wtA[i] = h2{(_Float16)((float)repa.x * w0),
                                (_Float16)((float)repa.y * w1)};
                    wtB[i] = h2{(_Float16)((float)repb.x * w2),
                                (_Float16)((float)repb.y * w3)};
                } else {
                    acc[i] = dot2_acc(repa, wtA[i], dot2_acc(repb, wtB[i], acc[i]));
                }
            }
        }
        __builtin_amdgcn_wave_barrier();
        x4 = xn4;
    }

    // ---- epilogue: 8-lane reduce, cross-wave combine, sigmoid -----------
#pragma unroll
    for (int i = 0; i < CSLOT; ++i) {
        int cell = g + 8*i;
        float v = acc[i];
        v += __shfl_xor(v, 1, 64);
        v += __shfl_xor(v, 2, 64);
        v += __shfl_xor(v, 4, 64);
        if (d4 == 0 && cell < NCELL) wscr[w].pRed[cell] = v;  // own-wave slot
    }
    __syncthreads();
    if (tid < NCELL) {
        float p = 0.f;
#pragma unroll
        for (int q = 0; q < NWAVE; ++q) p += wscr[q].pRed[tid];
        out[b*NCELL + tid] = 1.f / (1.f + expf(-(p*inv_len + bo)));
    }
}

extern "C" void kernel_launch(void* const* d_in, const int* in_sizes, int n_in,
                              void* d_out, int out_size, void* d_ws, size_t ws_size,
                              hipStream_t stream) {
    const float* ctx   = (const float*)d_in[0];
    const float* W1    = (const float*)d_in[1];
    const float* b1    = (const float*)d_in[2];
    const float* W2    = (const float*)d_in[3];
    const float* b2    = (const float*)d_in[4];
    const float* Wout  = (const float*)d_in[5];
    const float* bout  = (const float*)d_in[6];
    const int* item_idxs  = (const int*)d_in[7];
    const int* user_items = (const int*)d_in[8];
    const int* user_lens  = (const int*)d_in[9];
    float* out = (float*)d_out;
    float* ws  = (float*)d_ws;                 // uses 23,808 B
    int*   order = (int*)(ws + WS_ORDER);

    cnn_setup<<<NSEG + 1, 256, 0, stream>>>(W1, b1, W2, b2, user_lens, ws, order);
    cnn_main<<<BATCH, 512, 0, stream>>>(ctx, ws, Wout, bout,
                                        item_idxs, user_items, user_lens,
                                        order, out);
}

// Round 8
// 132.428 us; speedup vs baseline: 1.0192x; 1.0192x over previous
//
#include <hip/hip_runtime.h>
#include <math.h>

// Problem constants (fixed by the reference).
#define NITEMS 50000
#define BATCH  512
#define LLEN   50
#define KTOP   20
#define HDIM   32
#define DDIM   32
#define NCH    5
#define NSEG   33             // H+1 piecewise-linear segments
#define NSCAL  200            // scalars per item
#define NCELL  100            // (c,k) cells
#define THRP   33             // padded LDS stride for sorted thresholds
#define NWAVE  8              // waves per block
#define CSLOT  13             // ceil(100/8) cells per 8-lane group

typedef _Float16 h2 __attribute__((ext_vector_type(2)));

static __device__ __forceinline__ float dot2_acc(h2 a, h2 b, float c) {
#if __has_builtin(__builtin_amdgcn_fdot2)
    return __builtin_amdgcn_fdot2(a, b, c, false);
#else
    return fmaf((float)a.x, (float)b.x, fmaf((float)a.y, (float)b.y, c));
#endif
}

// ws layout (floats):
//   [0, 160)       sorted thr[c][0..31] (ascending per channel)
//   [160, 5440)    AB16 table: 5280 uints, fp16 swizzled (see below)
//   [5440, 5952)   row order (ints) from the length sort
#define WS_THRS  0
#define WS_AB16  160
#define WS_ORDER 5440

// fp16 table layout: row (c,s) = 32 uints (128 B).  Chunk d4 (0..7) = 4
// uints: [A(4d4,4d4+1), B(4d4,4d4+1), A(4d4+2,4d4+3), B(4d4+2,4d4+3)]
// where A(a,b) packs halves (lo=A_a, hi=A_b).  A lane's b128 read of its
// chunk is directly v_pk_fma_f16-ready.

// ---------------------------------------------------------------------------
// Setup + sort, one dispatch. Blocks 0..32: per-(channel, segment) affine
// coeffs of the scalar MLP (piecewise-linear decomposition; segment
// s = #{h : thr_h < x}), written as the swizzled fp16 table.  Block 0 also
// writes per-channel SORTED thresholds (sRank is the sort permutation).
// Block 33: bitonic sort of the 512 lens -> perf-only row permutation.
// ---------------------------------------------------------------------------
__global__ __launch_bounds__(256) void cnn_setup(
        const float* __restrict__ W1, const float* __restrict__ b1,
        const float* __restrict__ W2, const float* __restrict__ b2,
        const int* __restrict__ user_lens,
        float* __restrict__ ws, int* __restrict__ order) {
    const int tid = threadIdx.x;

    if (blockIdx.x < NSEG) {
        __shared__ float sW1[NCH*HDIM], sB1[NCH*HDIM], sThr[NCH*HDIM];
        __shared__ int   sRank[NCH*HDIM];
        __shared__ float sW2[NCH*HDIM*DDIM];     // 20 KB
        __shared__ float sB2[NCH*DDIM];

        for (int i = tid; i < NCH*HDIM; i += 256) { sW1[i] = W1[i]; sB1[i] = b1[i]; }
        for (int i = tid; i < NCH*HDIM*DDIM; i += 256) sW2[i] = W2[i];
        for (int i = tid; i < NCH*DDIM; i += 256) sB2[i] = b2[i];
        __syncthreads();

        for (int i = tid; i < NCH*HDIM; i += 256) {
            float w = sW1[i];
            sThr[i] = (w != 0.f) ? (-sB1[i] / w) : INFINITY;
        }
        __syncthreads();

        for (int i = tid; i < NCH*HDIM; i += 256) {
            int c = i / HDIM, h = i % HDIM;
            float thr = sThr[i];
            int rank = 0;
            for (int h2i = 0; h2i < HDIM; ++h2i) {
                float thr2 = sThr[c*HDIM + h2i];
                rank += (thr2 < thr || (thr2 == thr && h2i < h)) ? 1 : 0;
            }
            sRank[i] = rank;
            // sorted thresholds: sorted[rank] = thr  (rank is a permutation)
            if (blockIdx.x == 0) ws[WS_THRS + c*HDIM + rank] = thr;
        }
        __syncthreads();

        const int s = blockIdx.x;                 // segment
        if (tid < NCH*DDIM) {
            int c = tid / DDIM, d = tid % DDIM;
            float A = 0.f, Bv = 0.f;
#pragma unroll
            for (int h = 0; h < HDIM; ++h) {
                float w  = sW1[c*HDIM + h];
                float bb = sB1[c*HDIM + h];
                int   r  = sRank[c*HDIM + h];
                bool active = (w > 0.f) ? (r < s) : ((w < 0.f) ? (r >= s) : (bb > 0.f));
                if (active) {
                    float w2 = sW2[(c*HDIM + h)*DDIM + d];
                    A  = fmaf(w,  w2, A);
                    Bv = fmaf(bb, w2, Bv);
                }
            }
            Bv += sB2[c*DDIM + d];
            // swizzled fp16 store (see layout comment above)
            unsigned short* ab = (unsigned short*)(ws + WS_AB16);
            int d4 = d >> 2, dd = d & 3;
            int base = ((c*NSEG + s)*32 + d4*4)*2;          // ushort index
            _Float16 ah = (_Float16)A, bh = (_Float16)Bv;
            ab[base + 4*(dd>>1) + (dd&1)]     = __builtin_bit_cast(unsigned short, ah);
            ab[base + 4*(dd>>1) + 2 + (dd&1)] = __builtin_bit_cast(unsigned short, bh);
        }
    } else {
        // ---- bitonic sort of (len, row), 256 threads over 512 elements ----
        __shared__ int k512[BATCH], v512[BATCH];
        for (int i = tid; i < BATCH; i += 256) { k512[i] = user_lens[i]; v512[i] = i; }
        __syncthreads();
        for (int k = 2; k <= BATCH; k <<= 1) {
            for (int j = k >> 1; j > 0; j >>= 1) {
                int i   = ((tid & ~(j - 1)) << 1) | (tid & (j - 1));
                int ixj = i | j;
                bool up = ((i & k) == 0);
                int ka = k512[i], kb = k512[ixj];
                if ((ka > kb) == up) {
                    k512[i] = kb; k512[ixj] = ka;
                    int va = v512[i]; v512[i] = v512[ixj]; v512[ixj] = va;
                }
                __syncthreads();
            }
        }
        for (int i = tid; i < BATCH; i += 256) order[i] = v512[i];
    }
}

// ---------------------------------------------------------------------------
// Main (R8): R7's fp16-table / 8-lane-group structure, spill-proofed.
// R7 post-mortem: WRITE_SIZE 53 MB of scratch spills (the h2 wt arrays,
// conditionally written inside the dynamic j-loop, defeated AGPR promotion;
// VGPR_Count fell to 64 and ~12 dwords/thread/iter went to scratch).  R8:
// (1) the TARGET item is PEELED out of the loop -- wt written once in
// straight-line code; (2) wt held as plain uint arrays (bit-cast to h2 at
// use), which the allocator can park in AGPRs for free.
// ---------------------------------------------------------------------------
__global__ __launch_bounds__(512, 4) void cnn_main(
        const float* __restrict__ ctx,  const float* __restrict__ ws,
        const float* __restrict__ Wout, const float* __restrict__ bout,
        const int* __restrict__ item_idxs, const int* __restrict__ user_items,
        const int* __restrict__ user_lens, const int* __restrict__ order,
        float* __restrict__ out) {
    __shared__ unsigned int sAB16[NCH*NSEG*32];  // 21120 B, swizzled fp16
    __shared__ float  sThrS[NCH*THRP];           // sorted thr, stride 33
    __shared__ float4 sxo[NWAVE][NCELL];         // per-wave {x0,x1,off0|off1<<16,pad}
    __shared__ union WScr {                      // per-wave scratch (race-free:
        float rawx[NSCAL];                       //  own-wave use only)
        float pRed[NCELL];
    } wscr[NWAVE];

    const int tid  = threadIdx.x;
    const int w    = tid >> 6;              // wave 0..7
    const int lane = tid & 63;
    const int g    = lane >> 3;             // cell sub-group 0..7
    const int d4   = lane & 7;              // covers d = 4*d4 .. 4*d4+3

    // Stage fp16 table + sorted thresholds.
    const uint4* ABg = reinterpret_cast<const uint4*>(ws + WS_AB16);
    uint4* sAB4 = reinterpret_cast<uint4*>(sAB16);
    for (int i = tid; i < NCH*NSEG*8; i += 512) sAB4[i] = ABg[i];
    for (int i = tid; i < NCH*THRP; i += 512) {
        int c = i / THRP, j = i - c*THRP;
        sThrS[i] = (j < HDIM) ? ws[WS_THRS + c*HDIM + j] : 0.f;
    }

    // Sorted pairing (ranks r and 511-r co-resident under round-robin).
    const int rank = (blockIdx.x < 256) ? blockIdx.x : (767 - blockIdx.x);
    const int b    = order[rank];
    const int len  = user_lens[b];          // >= 1
    const float inv_len = 1.f / (float)len;
    const float bo = bout[0];
    const h2 wv0 = {(_Float16)Wout[4*d4],     (_Float16)Wout[4*d4 + 1]};
    const h2 wv1 = {(_Float16)Wout[4*d4 + 2], (_Float16)Wout[4*d4 + 3]};

    // Per-(lane,round) phase-S constants (fixed across items).
    int sc[4], sdx[4], sdo[4];
#pragma unroll
    for (int r = 0; r < 4; ++r) {
        int idx  = lane + 64*r;
        int c    = idx / 40, rr = idx - c*40;
        int cell = c*KTOP + (rr % KTOP);
        int p    = rr / KTOP;
        sc[r]  = c;
        sdx[r] = cell*16 + p*4;             // byte offset of x0/x1 in sxo[w]
        sdo[r] = cell*16 + 8 + p*2;         // byte offset of off half-word
    }

    const int nstripe = (len > w) ? ((len - w + NWAVE - 1) / NWAVE) : 0;

    unsigned int wtA[CSLOT], wtB[CSLOT];    // target rep * Wout (h2 bits)
    float acc[CSLOT];
#pragma unroll
    for (int i = 0; i < CSLOT; ++i) acc[i] = 0.f;

    __syncthreads();                        // staging visible to all waves

    char* sxoB = (char*)&sxo[w][0];

    // ======== peeled target item ========================================
    float4 x4 = make_float4(0.f, 0.f, 0.f, 0.f);
    {
        int it0 = item_idxs[b];
        if (lane < 50) x4 = *((const float4*)(ctx + (size_t)it0*NSCAL) + lane);
    }
    if (lane < 50) *((float4*)&wscr[w].rawx[0] + lane) = x4;
    __builtin_amdgcn_wave_barrier();

#pragma unroll
    for (int r = 0; r < 4; ++r) {
        int idx = lane + 64*r;
        if (idx < NSCAL) {
            float xv = wscr[w].rawx[idx];
            int base = sc[r]*THRP;
            int pos = 0;
            pos += (sThrS[base + pos + 15] < xv) ? 16 : 0;
            pos += (sThrS[base + pos + 7]  < xv) ? 8  : 0;
            pos += (sThrS[base + pos + 3]  < xv) ? 4  : 0;
            pos += (sThrS[base + pos + 1]  < xv) ? 2  : 0;
            pos += (sThrS[base + pos]      < xv) ? 1  : 0;
            int off = (sc[r]*NSEG + pos) << 7;   // byte offset of 128 B row
            *(float*)(sxoB + sdx[r]) = xv;
            *(unsigned short*)(sxoB + sdo[r]) = (unsigned short)off;
        }
    }
    __builtin_amdgcn_wave_barrier();

    // prefetch this wave's first stripe item while computing target phase C
    float4 xn4 = make_float4(0.f, 0.f, 0.f, 0.f);
    if (nstripe > 0) {
        int nit = user_items[b*LLEN + w];
        if (lane < 50) xn4 = *((const float4*)(ctx + (size_t)nit*NSCAL) + lane);
    }

#pragma unroll
    for (int i = 0; i < CSLOT; ++i) {
        int cell = g + 8*i;
        if (cell < NCELL) {
            float4 xo = sxo[w][cell];
            unsigned int offs = __builtin_bit_cast(unsigned int, xo.z);
            const uint4* p0 = (const uint4*)((const char*)sAB16 + (offs & 0xffffu) + (d4 << 4));
            const uint4* p1 = (const uint4*)((const char*)sAB16 + (offs >> 16)     + (d4 << 4));
            uint4 q0 = *p0, q1 = *p1;
            _Float16 x0h = (_Float16)xo.x, x1h = (_Float16)xo.y;
            h2 x0 = {x0h, x0h}, x1 = {x1h, x1h};
            h2 repa = (x0 * __builtin_bit_cast(h2, q0.x) + __builtin_bit_cast(h2, q0.y))
                    * (x1 * __builtin_bit_cast(h2, q1.x) + __builtin_bit_cast(h2, q1.y));
            h2 repb = (x0 * __builtin_bit_cast(h2, q0.z) + __builtin_bit_cast(h2, q0.w))
                    * (x1 * __builtin_bit_cast(h2, q1.z) + __builtin_bit_cast(h2, q1.w));
            wtA[i] = __builtin_bit_cast(unsigned int, (h2)(repa * wv0));
            wtB[i] = __builtin_bit_cast(unsigned int, (h2)(repb * wv1));
        }
    }
    __builtin_amdgcn_wave_barrier();
    x4 = xn4;

    // ======== stripe items (this wave only; no per-item barriers) ========
    for (int j = 0; j < nstripe; ++j) {
        if (lane < 50) *((float4*)&wscr[w].rawx[0] + lane) = x4;
        __builtin_amdgcn_wave_barrier();

        xn4 = make_float4(0.f, 0.f, 0.f, 0.f);
        if (j + 1 < nstripe) {
            int nit = user_items[b*LLEN + w + NWAVE*(j + 1)];
            if (lane < 50) xn4 = *((const float4*)(ctx + (size_t)nit*NSCAL) + lane);
        }

#pragma unroll
        for (int r = 0; r < 4; ++r) {
            int idx = lane + 64*r;
            if (idx < NSCAL) {
                float xv = wscr[w].rawx[idx];
                int base = sc[r]*THRP;
                int pos = 0;
                pos += (sThrS[base + pos + 15] < xv) ? 16 : 0;
                pos += (sThrS[base + pos + 7]  < xv) ? 8  : 0;
                pos += (sThrS[base + pos + 3]  < xv) ? 4  : 0;
                pos += (sThrS[base + pos + 1]  < xv) ? 2  : 0;
                pos += (sThrS[base + pos]      < xv) ? 1  : 0;
                int off = (sc[r]*NSEG + pos) << 7;
                *(float*)(sxoB + sdx[r]) = xv;
                *(unsigned short*)(sxoB + sdo[r]) = (unsigned short)off;
            }
        }
        __builtin_amdgcn_wave_barrier();

#pragma unroll
        for (int i = 0; i < CSLOT; ++i) {
            int cell = g + 8*i;
            if (cell < NCELL) {
                float4 xo = sxo[w][cell];
                unsigned int offs = __builtin_bit_cast(unsigned int, xo.z);
                const uint4* p0 = (const uint4*)((const char*)sAB16 + (offs & 0xffffu) + (d4 << 4));
                const uint4* p1 = (const uint4*)((const char*)sAB16 + (offs >> 16)     + (d4 << 4));
                uint4 q0 = *p0, q1 = *p1;
                _Float16 x0h = (_Float16)xo.x, x1h = (_Float16)xo.y;
                h2 x0 = {x0h, x0h}, x1 = {x1h, x1h};
                h2 repa = (x0 * __builtin_bit_cast(h2, q0.x) + __builtin_bit_cast(h2, q0.y))
                        * (x1 * __builtin_bit_cast(h2, q1.x) + __builtin_bit_cast(h2, q1.y));
                h2 repb = (x0 * __builtin_bit_cast(h2, q0.z) + __builtin_bit_cast(h2, q0.w))
                        * (x1 * __builtin_bit_cast(h2, q1.z) + __builtin_bit_cast(h2, q1.w));
                acc[i] = dot2_acc(repa, __builtin_bit_cast(h2, wtA[i]),
                         dot2_acc(repb, __builtin_bit_cast(h2, wtB[i]), acc[i]));
            }
        }
        __builtin_amdgcn_wave_barrier();
        x4 = xn4;
    }

    // ---- epilogue: 8-lane reduce, cross-wave combine, sigmoid -----------
#pragma unroll
    for (int i = 0; i < CSLOT; ++i) {
        int cell = g + 8*i;
        float v = acc[i];
        v += __shfl_xor(v, 1, 64);
        v += __shfl_xor(v, 2, 64);
        v += __shfl_xor(v, 4, 64);
        if (d4 == 0 && cell < NCELL) wscr[w].pRed[cell] = v;  // own-wave slot
    }
    __syncthreads();
    if (tid < NCELL) {
        float p = 0.f;
#pragma unroll
        for (int q = 0; q < NWAVE; ++q) p += wscr[q].pRed[tid];
        out[b*NCELL + tid] = 1.f / (1.f + expf(-(p*inv_len + bo)));
    }
}

extern "C" void kernel_launch(void* const* d_in, const int* in_sizes, int n_in,
                              void* d_out, int out_size, void* d_ws, size_t ws_size,
                              hipStream_t stream) {
    const float* ctx   = (const float*)d_in[0];
    const float* W1    = (const float*)d_in[1];
    const float* b1    = (const float*)d_in[2];
    const float* W2    = (const float*)d_in[3];
    const float* b2    = (const float*)d_in[4];
    const float* Wout  = (const float*)d_in[5];
    const float* bout  = (const float*)d_in[6];
    const int* item_idxs  = (const int*)d_in[7];
    const int* user_items = (const int*)d_in[8];
    const int* user_lens  = (const int*)d_in[9];
    float* out = (float*)d_out;
    float* ws  = (float*)d_ws;                 // uses 23,808 B
    int*   order = (int*)(ws + WS_ORDER);

    cnn_setup<<<NSEG + 1, 256, 0, stream>>>(W1, b1, W2, b2, user_lens, ws, order);
    cnn_main<<<BATCH, 512, 0, stream>>>(ctx, ws, Wout, bout,
                                        item_idxs, user_items, user_lens,
                                        order, out);
}

// Round 9
// 115.292 us; speedup vs baseline: 1.1706x; 1.1486x over previous
//
#include <hip/hip_runtime.h>
#include <math.h>

// Problem constants (fixed by the reference).
#define NITEMS 50000
#define BATCH  512
#define LLEN   50
#define KTOP   20
#define HDIM   32
#define DDIM   32
#define NCH    5
#define NSEG   33             // H+1 piecewise-linear segments
#define NSCAL  200            // scalars per item
#define NCELL  100            // (c,k) cells
#define THRP   33             // padded LDS stride for sorted thresholds
#define NWAVE  8              // waves per block
#define CSLOT  13             // ceil(100/8) cells per 8-lane group

typedef _Float16 h2 __attribute__((ext_vector_type(2)));

static __device__ __forceinline__ float dot2_acc(h2 a, h2 b, float c) {
#if __has_builtin(__builtin_amdgcn_fdot2)
    return __builtin_amdgcn_fdot2(a, b, c, false);
#else
    return fmaf((float)a.x, (float)b.x, fmaf((float)a.y, (float)b.y, c));
#endif
}

// ws layout (floats):
//   [0, 160)       sorted thr[c][0..31] (ascending per channel)
//   [160, 5440)    AB16 table: 5280 uints, fp16 swizzled (see below)
//   [5440, 5952)   row order (ints) from the length sort
#define WS_THRS  0
#define WS_AB16  160
#define WS_ORDER 5440

// fp16 table layout: row (c,s) = 32 uints (128 B).  Chunk d4 (0..7) = 4
// uints: [A(4d4,4d4+1), B(4d4,4d4+1), A(4d4+2,4d4+3), B(4d4+2,4d4+3)]
// where A(a,b) packs halves (lo=A_a, hi=A_b).  A lane's b128 read of its
// chunk is directly v_pk_fma_f16-ready.

// ---------------------------------------------------------------------------
// Setup + sort, one dispatch (unchanged from R8). Blocks 0..32: affine
// coeffs of the scalar MLP per (channel, segment); block 0 also writes the
// per-channel SORTED thresholds.  Block 33: bitonic length sort (perf-only).
// ---------------------------------------------------------------------------
__global__ __launch_bounds__(256) void cnn_setup(
        const float* __restrict__ W1, const float* __restrict__ b1,
        const float* __restrict__ W2, const float* __restrict__ b2,
        const int* __restrict__ user_lens,
        float* __restrict__ ws, int* __restrict__ order) {
    const int tid = threadIdx.x;

    if (blockIdx.x < NSEG) {
        __shared__ float sW1[NCH*HDIM], sB1[NCH*HDIM], sThr[NCH*HDIM];
        __shared__ int   sRank[NCH*HDIM];
        __shared__ float sW2[NCH*HDIM*DDIM];     // 20 KB
        __shared__ float sB2[NCH*DDIM];

        for (int i = tid; i < NCH*HDIM; i += 256) { sW1[i] = W1[i]; sB1[i] = b1[i]; }
        for (int i = tid; i < NCH*HDIM*DDIM; i += 256) sW2[i] = W2[i];
        for (int i = tid; i < NCH*DDIM; i += 256) sB2[i] = b2[i];
        __syncthreads();

        for (int i = tid; i < NCH*HDIM; i += 256) {
            float w = sW1[i];
            sThr[i] = (w != 0.f) ? (-sB1[i] / w) : INFINITY;
        }
        __syncthreads();

        for (int i = tid; i < NCH*HDIM; i += 256) {
            int c = i / HDIM, h = i % HDIM;
            float thr = sThr[i];
            int rank = 0;
            for (int h2i = 0; h2i < HDIM; ++h2i) {
                float thr2 = sThr[c*HDIM + h2i];
                rank += (thr2 < thr || (thr2 == thr && h2i < h)) ? 1 : 0;
            }
            sRank[i] = rank;
            if (blockIdx.x == 0) ws[WS_THRS + c*HDIM + rank] = thr;
        }
        __syncthreads();

        const int s = blockIdx.x;                 // segment
        if (tid < NCH*DDIM) {
            int c = tid / DDIM, d = tid % DDIM;
            float A = 0.f, Bv = 0.f;
#pragma unroll
            for (int h = 0; h < HDIM; ++h) {
                float w  = sW1[c*HDIM + h];
                float bb = sB1[c*HDIM + h];
                int   r  = sRank[c*HDIM + h];
                bool active = (w > 0.f) ? (r < s) : ((w < 0.f) ? (r >= s) : (bb > 0.f));
                if (active) {
                    float w2 = sW2[(c*HDIM + h)*DDIM + d];
                    A  = fmaf(w,  w2, A);
                    Bv = fmaf(bb, w2, Bv);
                }
            }
            Bv += sB2[c*DDIM + d];
            unsigned short* ab = (unsigned short*)(ws + WS_AB16);
            int d4 = d >> 2, dd = d & 3;
            int base = ((c*NSEG + s)*32 + d4*4)*2;          // ushort index
            _Float16 ah = (_Float16)A, bh = (_Float16)Bv;
            ab[base + 4*(dd>>1) + (dd&1)]     = __builtin_bit_cast(unsigned short, ah);
            ab[base + 4*(dd>>1) + 2 + (dd&1)] = __builtin_bit_cast(unsigned short, bh);
        }
    } else {
        // ---- bitonic sort of (len, row), 256 threads over 512 elements ----
        __shared__ int k512[BATCH], v512[BATCH];
        for (int i = tid; i < BATCH; i += 256) { k512[i] = user_lens[i]; v512[i] = i; }
        __syncthreads();
        for (int k = 2; k <= BATCH; k <<= 1) {
            for (int j = k >> 1; j > 0; j >>= 1) {
                int i   = ((tid & ~(j - 1)) << 1) | (tid & (j - 1));
                int ixj = i | j;
                bool up = ((i & k) == 0);
                int ka = k512[i], kb = k512[ixj];
                if ((ka > kb) == up) {
                    k512[i] = kb; k512[ixj] = ka;
                    int va = v512[i]; v512[i] = v512[ixj]; v512[ixj] = va;
                }
                __syncthreads();
            }
        }
        for (int i = tid; i < BATCH; i += 256) order[i] = v512[i];
    }
}

// ---------------------------------------------------------------------------
// Main (R9): R8 post-mortem -- LDS pipe (one per CU, ~per-inst rates) is the
// floor, and 24% of item-units were redundant target evals.  Changes:
//  (1) ONE wave computes the target rep*Wout and broadcasts it via sWt
//      (6.4 KB LDS); other waves register-load it once.  Units/CU 67->53.
//  (2) Phase S reads x DIRECTLY from global (coalesced per-lane dwords,
//      prefetched one item ahead) -- no LDS staging write/re-read.
//  (3) sxo entry packed to one dword per scalar {fp16(x) | rowoff<<16}:
//      4 writes/unit (was 8), phase-C broadcast b64 (was b128).  x was
//      converted to fp16 in phase C anyway -- zero added error.
// ---------------------------------------------------------------------------
__global__ __launch_bounds__(512, 4) void cnn_main(
        const float* __restrict__ ctx,  const float* __restrict__ ws,
        const float* __restrict__ Wout, const float* __restrict__ bout,
        const int* __restrict__ item_idxs, const int* __restrict__ user_items,
        const int* __restrict__ user_lens, const int* __restrict__ order,
        float* __restrict__ out) {
    __shared__ unsigned int sAB16[NCH*NSEG*32];  // 21120 B, swizzled fp16
    __shared__ float  sThrS[NCH*THRP];           // sorted thr, stride 33
    __shared__ uint2  sxo[NWAVE][NCELL];         // {x0h|off0<<16, x1h|off1<<16}
    __shared__ uint2  sWt[NCELL*8];              // [cell*8+d4] target wt bits
    __shared__ float  pRed[NWAVE][NCELL];        // per-wave scalar partials

    const int tid  = threadIdx.x;
    const int w    = tid >> 6;              // wave 0..7
    const int lane = tid & 63;
    const int g    = lane >> 3;             // cell sub-group 0..7
    const int d4   = lane & 7;              // covers d = 4*d4 .. 4*d4+3

    // Stage fp16 table + sorted thresholds.
    const uint4* ABg = reinterpret_cast<const uint4*>(ws + WS_AB16);
    uint4* sAB4 = reinterpret_cast<uint4*>(sAB16);
    for (int i = tid; i < NCH*NSEG*8; i += 512) sAB4[i] = ABg[i];
    for (int i = tid; i < NCH*THRP; i += 512) {
        int c = i / THRP, j = i - c*THRP;
        sThrS[i] = (j < HDIM) ? ws[WS_THRS + c*HDIM + j] : 0.f;
    }

    // Sorted pairing (ranks r and 511-r co-resident under round-robin).
    const int rank = (blockIdx.x < 256) ? blockIdx.x : (767 - blockIdx.x);
    const int b    = order[rank];
    const int len  = user_lens[b];          // >= 1
    const float inv_len = 1.f / (float)len;
    const float bo = bout[0];
    const h2 wv0 = {(_Float16)Wout[4*d4],     (_Float16)Wout[4*d4 + 1]};
    const h2 wv1 = {(_Float16)Wout[4*d4 + 2], (_Float16)Wout[4*d4 + 3]};

    // Per-(lane,round) phase-S constants (fixed across items).
    int sc[4], sdst[4];
#pragma unroll
    for (int r = 0; r < 4; ++r) {
        int idx  = lane + 64*r;
        int c    = idx / 40, rr = idx - c*40;
        int cell = c*KTOP + (rr % KTOP);
        sc[r]   = c;
        sdst[r] = cell*8 + (rr / KTOP)*4;   // byte offset in sxo[w]
    }

    const int nstripe = (len > w) ? ((len - w + NWAVE - 1) / NWAVE) : 0;

    unsigned int wtA[CSLOT], wtB[CSLOT];    // target rep * Wout (h2 bits)
    float acc[CSLOT];
#pragma unroll
    for (int i = 0; i < CSLOT; ++i) acc[i] = 0.f;

    char* sxoB = (char*)&sxo[w][0];

    __syncthreads();                        // staging visible to all waves

    // Prefetch this wave's first stripe item (overlaps wave 0's target).
    float xp[4] = {0.f, 0.f, 0.f, 0.f};
    if (nstripe > 0) {
        const float* row = ctx + (size_t)user_items[b*LLEN + w] * NSCAL;
#pragma unroll
        for (int r = 0; r < 4; ++r) {
            int idx = lane + 64*r;
            if (idx < NSCAL) xp[r] = row[idx];
        }
    }

    // ======== target item: wave 0 only, broadcast via sWt ================
    if (w == 0) {
        float xt[4] = {0.f, 0.f, 0.f, 0.f};
        const float* row = ctx + (size_t)item_idxs[b] * NSCAL;
#pragma unroll
        for (int r = 0; r < 4; ++r) {
            int idx = lane + 64*r;
            if (idx < NSCAL) xt[r] = row[idx];
        }
#pragma unroll
        for (int r = 0; r < 4; ++r) {
            int idx = lane + 64*r;
            if (idx < NSCAL) {
                float xv = xt[r];
                int base = sc[r]*THRP;
                int pos = 0;
                pos += (sThrS[base + pos + 15] < xv) ? 16 : 0;
                pos += (sThrS[base + pos + 7]  < xv) ? 8  : 0;
                pos += (sThrS[base + pos + 3]  < xv) ? 4  : 0;
                pos += (sThrS[base + pos + 1]  < xv) ? 2  : 0;
                pos += (sThrS[base + pos]      < xv) ? 1  : 0;
                unsigned int off = (unsigned int)((sc[r]*NSEG + pos) << 7);
                _Float16 xh = (_Float16)xv;
                unsigned int word = (unsigned int)__builtin_bit_cast(unsigned short, xh)
                                  | (off << 16);
                *(unsigned int*)(sxoB + sdst[r]) = word;
            }
        }
        __builtin_amdgcn_wave_barrier();
#pragma unroll
        for (int i = 0; i < CSLOT; ++i) {
            int cell = g + 8*i;
            if (cell < NCELL) {
                uint2 xo = sxo[0][cell];
                const uint4* p0 = (const uint4*)((const char*)sAB16 + (xo.x >> 16) + (d4 << 4));
                const uint4* p1 = (const uint4*)((const char*)sAB16 + (xo.y >> 16) + (d4 << 4));
                uint4 q0 = *p0, q1 = *p1;
                _Float16 x0h = __builtin_bit_cast(_Float16, (unsigned short)(xo.x & 0xffffu));
                _Float16 x1h = __builtin_bit_cast(_Float16, (unsigned short)(xo.y & 0xffffu));
                h2 x0 = {x0h, x0h}, x1 = {x1h, x1h};
                h2 repa = (x0 * __builtin_bit_cast(h2, q0.x) + __builtin_bit_cast(h2, q0.y))
                        * (x1 * __builtin_bit_cast(h2, q1.x) + __builtin_bit_cast(h2, q1.y));
                h2 repb = (x0 * __builtin_bit_cast(h2, q0.z) + __builtin_bit_cast(h2, q0.w))
                        * (x1 * __builtin_bit_cast(h2, q1.z) + __builtin_bit_cast(h2, q1.w));
                wtA[i] = __builtin_bit_cast(unsigned int, (h2)(repa * wv0));
                wtB[i] = __builtin_bit_cast(unsigned int, (h2)(repb * wv1));
                sWt[cell*8 + d4] = make_uint2(wtA[i], wtB[i]);
            }
        }
    }
    __syncthreads();                        // sWt ready for all waves

    if (w != 0) {
#pragma unroll
        for (int i = 0; i < CSLOT; ++i) {
            int cell = g + 8*i;
            if (cell < NCELL) {
                uint2 v = sWt[cell*8 + d4];
                wtA[i] = v.x; wtB[i] = v.y;
            }
        }
    }

    // ======== stripe items (this wave only; no per-item barriers) ========
    for (int j = 0; j < nstripe; ++j) {
        float xc[4];
#pragma unroll
        for (int r = 0; r < 4; ++r) xc[r] = xp[r];

        // prefetch next stripe item (latency hidden behind S+C)
        if (j + 1 < nstripe) {
            const float* row = ctx + (size_t)user_items[b*LLEN + w + NWAVE*(j+1)] * NSCAL;
#pragma unroll
            for (int r = 0; r < 4; ++r) {
                int idx = lane + 64*r;
                if (idx < NSCAL) xp[r] = row[idx];
            }
        }

        // ---- phase S: binary-search segment, pack {fp16(x)|rowoff} ------
#pragma unroll
        for (int r = 0; r < 4; ++r) {
            int idx = lane + 64*r;
            if (idx < NSCAL) {
                float xv = xc[r];
                int base = sc[r]*THRP;
                int pos = 0;
                pos += (sThrS[base + pos + 15] < xv) ? 16 : 0;
                pos += (sThrS[base + pos + 7]  < xv) ? 8  : 0;
                pos += (sThrS[base + pos + 3]  < xv) ? 4  : 0;
                pos += (sThrS[base + pos + 1]  < xv) ? 2  : 0;
                pos += (sThrS[base + pos]      < xv) ? 1  : 0;
                unsigned int off = (unsigned int)((sc[r]*NSEG + pos) << 7);
                _Float16 xh = (_Float16)xv;
                unsigned int word = (unsigned int)__builtin_bit_cast(unsigned short, xh)
                                  | (off << 16);
                *(unsigned int*)(sxoB + sdst[r]) = word;
            }
        }
        __builtin_amdgcn_wave_barrier();

        // ---- phase C: 100 cells x 32 d by this wave alone ----------------
#pragma unroll
        for (int i = 0; i < CSLOT; ++i) {
            int cell = g + 8*i;
            if (cell < NCELL) {
                uint2 xo = sxo[w][cell];
                const uint4* p0 = (const uint4*)((const char*)sAB16 + (xo.x >> 16) + (d4 << 4));
                const uint4* p1 = (const uint4*)((const char*)sAB16 + (xo.y >> 16) + (d4 << 4));
                uint4 q0 = *p0, q1 = *p1;
                _Float16 x0h = __builtin_bit_cast(_Float16, (unsigned short)(xo.x & 0xffffu));
                _Float16 x1h = __builtin_bit_cast(_Float16, (unsigned short)(xo.y & 0xffffu));
                h2 x0 = {x0h, x0h}, x1 = {x1h, x1h};
                h2 repa = (x0 * __builtin_bit_cast(h2, q0.x) + __builtin_bit_cast(h2, q0.y))
                        * (x1 * __builtin_bit_cast(h2, q1.x) + __builtin_bit_cast(h2, q1.y));
                h2 repb = (x0 * __builtin_bit_cast(h2, q0.z) + __builtin_bit_cast(h2, q0.w))
                        * (x1 * __builtin_bit_cast(h2, q1.z) + __builtin_bit_cast(h2, q1.w));
                acc[i] = dot2_acc(repa, __builtin_bit_cast(h2, wtA[i]),
                         dot2_acc(repb, __builtin_bit_cast(h2, wtB[i]), acc[i]));
            }
        }
        __builtin_amdgcn_wave_barrier();
    }

    // ---- epilogue: 8-lane reduce, cross-wave combine, sigmoid -----------
#pragma unroll
    for (int i = 0; i < CSLOT; ++i) {
        int cell = g + 8*i;
        float v = acc[i];
        v += __shfl_xor(v, 1, 64);
        v += __shfl_xor(v, 2, 64);
        v += __shfl_xor(v, 4, 64);
        if (d4 == 0 && cell < NCELL) pRed[w][cell] = v;
    }
    __syncthreads();
    if (tid < NCELL) {
        float p = 0.f;
#pragma unroll
        for (int q = 0; q < NWAVE; ++q) p += pRed[q][tid];
        out[b*NCELL + tid] = 1.f / (1.f + expf(-(p*inv_len + bo)));
    }
}

extern "C" void kernel_launch(void* const* d_in, const int* in_sizes, int n_in,
                              void* d_out, int out_size, void* d_ws, size_t ws_size,
                              hipStream_t stream) {
    const float* ctx   = (const float*)d_in[0];
    const float* W1    = (const float*)d_in[1];
    const float* b1    = (const float*)d_in[2];
    const float* W2    = (const float*)d_in[3];
    const float* b2    = (const float*)d_in[4];
    const float* Wout  = (const float*)d_in[5];
    const float* bout  = (const float*)d_in[6];
    const int* item_idxs  = (const int*)d_in[7];
    const int* user_items = (const int*)d_in[8];
    const int* user_lens  = (const int*)d_in[9];
    float* out = (float*)d_out;
    float* ws  = (float*)d_ws;                 // uses 23,808 B
    int*   order = (int*)(ws + WS_ORDER);

    cnn_setup<<<NSEG + 1, 256, 0, stream>>>(W1, b1, W2, b2, user_lens, ws, order);
    cnn_main<<<BATCH, 512, 0, stream>>>(ctx, ws, Wout, bout,
                                        item_idxs, user_items, user_lens,
                                        order, out);
}